// Round 14
// baseline (91.462 us; speedup 1.0000x reference)
//
#include <hip/hip_runtime.h>

// NT-Xent loss, fused: never materialize the 8192x8192 similarity matrix.
// z = concat(z1,z2) [8192,256] f32 -> normalize -> fp8 e4m3 zn8 (ws)
// S = zn8 zn8^T via mfma_f32_16x16x32_fp8_fp8, fused per-row sum of
// exp(2*cos - 2) (fixed logsumexp max = 2: logits bounded -> partials additive)
// nll_r = -pos_r + 2 + log(sum_r); out = mean(nll)
//
// R14 = R11 (verified 42.3us simlse) + T3/T4/T5 pipeline done with
// COMPILE-TIME buffer indices (R5's regression was runtime %3 -> scratch
// spill). 3 static 8KB buffers; #pragma unroll over all 16 phases; per
// phase: s_waitcnt vmcnt(2) [never 0 until last] -> s_barrier ->
// sched_barrier(0) -> stage(ph+2) -> setprio(1) MFMA cluster setprio(0)
// + epilogue. One barrier/phase; the per-phase vmcnt(0)+lgkmcnt(0) drain
// of __syncthreads (the ~37% no-issue gap) is gone.

#define NHALF 4096
#define N2 8192
#define D 256
#define CSPLIT 16
#define NPH 16      // phases per chunk; 2 tiles (32 cols) per phase
#define RPB 128     // rows per block (4 waves x 32)

typedef __attribute__((ext_vector_type(4))) float f32x4;

__device__ __forceinline__ unsigned char f2fp8(float f) {
  // OCP e4m3fn, RNE; inputs |f| <= 1 (normalized rows): no sat/NaN path.
  unsigned int u = __float_as_uint(f);
  unsigned char s = (unsigned char)((u >> 24) & 0x80u);
  int e = (int)((u >> 23) & 0xffu) - 127;
  unsigned int m = u & 0x7fffffu;
  if (e >= -6) {
    unsigned int r = m + 0x7ffffu + ((m >> 20) & 1u);
    if (r >= 0x800000u) { r = 0; ++e; } else r >>= 20;
    return (unsigned char)(s | (unsigned int)((e + 7) << 3) | r);
  }
  int q = (int)rintf(fabsf(f) * 512.0f);
  return (unsigned char)(s | (unsigned int)q);
}

__device__ __forceinline__ void gload_lds16(const void* g, void* l) {
  __builtin_amdgcn_global_load_lds(
      (const __attribute__((address_space(1))) unsigned int*)g,
      (__attribute__((address_space(3))) unsigned int*)l, 16, 0, 0);
}

// ---------------- Kernel 1: row-normalize to fp8 ----------------
__global__ __launch_bounds__(256) void norm_kernel(const float* __restrict__ z1,
                                                   const float* __restrict__ z2,
                                                   unsigned char* __restrict__ zn8) {
  const int lane = threadIdx.x & 63;
  const int row = blockIdx.x * 4 + (threadIdx.x >> 6);
  const float* src = (row < NHALF) ? (z1 + (size_t)row * D)
                                   : (z2 + (size_t)(row - NHALF) * D);
  const float4 v = *(const float4*)(src + lane * 4);
  float ss = v.x * v.x + v.y * v.y + v.z * v.z + v.w * v.w;
  #pragma unroll
  for (int m = 1; m < 64; m <<= 1) ss += __shfl_xor(ss, m);
  const float inv = 1.0f / fmaxf(sqrtf(ss), 1e-8f);
  unsigned int o = (unsigned int)f2fp8(v.x * inv) |
                   ((unsigned int)f2fp8(v.y * inv) << 8) |
                   ((unsigned int)f2fp8(v.z * inv) << 16) |
                   ((unsigned int)f2fp8(v.w * inv) << 24);
  *(unsigned int*)(zn8 + (size_t)row * D + lane * 4) = o;
}

// ---------------- Kernel 2: fused Gram + partial exp-sums ----------------
// grid (64 row-blocks, 16 col-chunks), 256 threads = 4 waves.
// Wave owns 32 rows = 2 stripes of 16; A in regs (32 VGPR); B in LDS.
// mfma_f32_16x16x32_fp8_fp8: A/B lane l -> row/col (l&15), k-bytes
//   8*(l>>4)..+7; D lane l -> col (l&15), row 4*(l>>4)+g. (R10/R11-verified.)
// LDS B: 3 static buffers x [2 tiles][16 cols][256 B]; swizzle
// inner ^= (col&3)<<5 on stage source AND ds_read (rule #21).
__global__ __launch_bounds__(256, 4) void simlse_kernel(const unsigned char* __restrict__ zn8,
                                                        float* __restrict__ sum_ws,
                                                        float* __restrict__ pos_ws) {
  __shared__ __align__(16) char bsm[24576];  // 3 x 8 KB
  const int lane = threadIdx.x & 63;
  const int wave = threadIdx.x >> 6;
  const int r16 = lane & 15;
  const int h = lane >> 4;  // 0..3
  const int rowbase = blockIdx.x * RPB + wave * 32;
  const int cc = blockIdx.y;

  // A fragments: 2 stripes x 8 K-steps, 8B contiguous per lane (32 VGPR).
  long a[2][8];
  #pragma unroll
  for (int st = 0; st < 2; ++st) {
    const unsigned char* ap = zn8 + (size_t)(rowbase + st * 16 + r16) * D + h * 8;
    #pragma unroll
    for (int s = 0; s < 8; ++s) a[st][s] = *(const long*)(ap + s * 32);
  }
  #pragma unroll
  for (int st = 0; st < 2; ++st)
    #pragma unroll
    for (int s = 0; s < 8; ++s) asm volatile("" : "+v"(a[st][s]));

  float lsum[2][4];
  #pragma unroll
  for (int st = 0; st < 2; ++st)
    #pragma unroll
    for (int g = 0; g < 4; ++g) lsum[st][g] = 0.0f;

  int dt[2], pt[2];
  #pragma unroll
  for (int st = 0; st < 2; ++st) {
    dt[st] = (rowbase + st * 16) >> 4;                      // diagonal tile
    pt[st] = ((rowbase + st * 16 + NHALF) & (N2 - 1)) >> 4; // positive tile
  }

  // Stage 2 tiles (8 KB) into LDS buffer `buf` (compile-time). Linear y in
  // [0,8192): tile = y>>12, col = (y>>8)&15, inner = y&255;
  // src inner ^= (col&3)<<5 (involution, 16B-aligned).
  auto stage = [&](int buf, int ph) {
    const int colbase = cc * 512 + ph * 32;
    #pragma unroll
    for (int s = 0; s < 2; ++s) {
      const int y = s * 4096 + wave * 1024 + lane * 16;
      const int col = (y >> 8) & 15;
      const int inner = (y & 255) ^ ((col & 3) << 5);
      const void* gp = zn8 + (size_t)(colbase + (y >> 12) * 16 + col) * D + inner;
      void* lp = bsm + buf * 8192 + s * 4096 + wave * 1024;  // +lane*16 by HW
      gload_lds16(gp, lp);
    }
  };

  // T3+T4: 2-deep DMA pipeline, counted vmcnt, one barrier per phase.
  // Each stage = 2 VMEM insts/lane; steady state outstanding at the wait
  // point = stage(ph)+stage(ph+1) = 4 -> vmcnt(2) retires stage(ph).
  stage(0, 0);
  stage(1, 1);
  #pragma unroll
  for (int ph = 0; ph < NPH; ++ph) {
    if (ph + 1 < NPH) {
      asm volatile("s_waitcnt vmcnt(2)");
    } else {
      asm volatile("s_waitcnt vmcnt(0)");
    }
    __builtin_amdgcn_s_barrier();        // buffer ph%3 fully staged block-wide
    __builtin_amdgcn_sched_barrier(0);   // rule #18: no hoisting past the wait
    if (ph + 2 < NPH) stage((ph + 2) % 3, ph + 2);  // compile-time index
    const char* base = bsm + (ph % 3) * 8192;
    #pragma unroll
    for (int j = 0; j < 2; ++j) {
      const int ct = cc * 32 + ph * 2 + j;
      const char* tb = base + j * 4096 + r16 * 256;
      const int sw = (r16 & 3) << 5;
      f32x4 acc0 = (f32x4){0.f, 0.f, 0.f, 0.f};
      f32x4 acc1 = (f32x4){0.f, 0.f, 0.f, 0.f};
      __builtin_amdgcn_s_setprio(1);
      #pragma unroll
      for (int s = 0; s < 8; ++s) {
        const long b = *(const long*)(tb + ((s * 32 + h * 8) ^ sw));
        acc0 = __builtin_amdgcn_mfma_f32_16x16x32_fp8_fp8(a[0][s], b, acc0, 0, 0, 0);
        acc1 = __builtin_amdgcn_mfma_f32_16x16x32_fp8_fp8(a[1][s], b, acc1, 0, 0, 0);
      }
      __builtin_amdgcn_s_setprio(0);
      #pragma unroll
      for (int st = 0; st < 2; ++st) {
        const f32x4& acc = st ? acc1 : acc0;
        const bool isd = (ct == dt[st]);
        const bool isp = (ct == pt[st]);
        if (!isd && !isp) {
          #pragma unroll
          for (int g = 0; g < 4; ++g)
            lsum[st][g] += __expf(fmaf(acc[g], 2.0f, -2.0f));
        } else {
          #pragma unroll
          for (int g = 0; g < 4; ++g) {
            const int rl = (h << 2) + g;    // local row 0..15
            const bool hit = (r16 == rl);   // tile-diagonal element
            float e = __expf(fmaf(acc[g], 2.0f, -2.0f));
            if (isd && hit) e = 0.0f;       // mask self-similarity
            if (isp && hit) pos_ws[rowbase + st * 16 + rl] = acc[g] * 2.0f;
            lsum[st][g] += e;
          }
        }
      }
    }
    // No trailing barrier: buffer ph%3 is next written by the stage issued
    // AFTER the (ph+1) barrier, and each wave's ds_reads retired before its
    // MFMAs consumed them -> no read-vs-DMA overlap is possible.
  }

  // Reduce exp-sums across each 16-lane column group.
  #pragma unroll
  for (int st = 0; st < 2; ++st)
    #pragma unroll
    for (int g = 0; g < 4; ++g) {
      #pragma unroll
      for (int m = 1; m < 16; m <<= 1)
        lsum[st][g] += __shfl_xor(lsum[st][g], m);
    }
  if (r16 == 0) {
    #pragma unroll
    for (int st = 0; st < 2; ++st)
      #pragma unroll
      for (int g = 0; g < 4; ++g) {
        const int r = rowbase + st * 16 + (h << 2) + g;
        sum_ws[(size_t)r * CSPLIT + cc] = lsum[st][g];
      }
  }
}

// ---------------- Kernel 3a: per-row nll + per-block partial sum ----------------
__global__ __launch_bounds__(256) void nll_kernel(const float* __restrict__ sum_ws,
                                                  const float* __restrict__ pos_ws,
                                                  float* __restrict__ partial) {
  const int r = blockIdx.x * 256 + threadIdx.x;
  const float4* sp = (const float4*)(sum_ws + (size_t)r * CSPLIT);
  float t = 0.0f;
  #pragma unroll
  for (int i = 0; i < CSPLIT / 4; ++i) {
    const float4 v = sp[i];
    t += v.x + v.y + v.z + v.w;
  }
  float nll = -pos_ws[r] + 2.0f + __logf(t);
  #pragma unroll
  for (int m = 1; m < 64; m <<= 1) nll += __shfl_xor(nll, m);
  __shared__ float red[4];
  const int lane = threadIdx.x & 63;
  const int wave = threadIdx.x >> 6;
  if (lane == 0) red[wave] = nll;
  __syncthreads();
  if (threadIdx.x == 0) partial[blockIdx.x] = red[0] + red[1] + red[2] + red[3];
}

// ---------------- Kernel 3b: final mean ----------------
__global__ __launch_bounds__(64) void final_kernel(const float* __restrict__ partial,
                                                   float* __restrict__ out) {
  const int lane = threadIdx.x;
  float v = (lane < 32) ? partial[lane] : 0.0f;
  #pragma unroll
  for (int m = 1; m < 64; m <<= 1) v += __shfl_xor(v, m);
  if (lane == 0) out[0] = v * (1.0f / (float)N2);
}

extern "C" void kernel_launch(void* const* d_in, const int* in_sizes, int n_in,
                              void* d_out, int out_size, void* d_ws, size_t ws_size,
                              hipStream_t stream) {
  const float* z1 = (const float*)d_in[0];
  const float* z2 = (const float*)d_in[1];
  float* out = (float*)d_out;

  char* ws = (char*)d_ws;
  unsigned char* zn8 = (unsigned char*)ws;                  // 8192*256 = 2 MB
  float* sum_ws = (float*)(ws + (size_t)N2 * D);            // 8192*16*4 = 512 KB
  float* pos_ws = sum_ws + (size_t)N2 * CSPLIT;             // 8192*4 = 32 KB
  float* partial = pos_ws + N2;                             // 32 floats

  hipLaunchKernelGGL(norm_kernel, dim3(N2 / 4), dim3(256), 0, stream, z1, z2, zn8);
  hipLaunchKernelGGL(simlse_kernel, dim3(N2 / RPB, CSPLIT), dim3(256), 0, stream,
                     zn8, sum_ws, pos_ws);
  hipLaunchKernelGGL(nll_kernel, dim3(N2 / 256), dim3(256), 0, stream, sum_ws, pos_ws, partial);
  hipLaunchKernelGGL(final_kernel, dim3(1), dim3(64), 0, stream, partial, out);
}

// Round 15
// 42.285 us; speedup vs baseline: 2.1630x; 2.1630x over previous
//
#include <hip/hip_runtime.h>

// NT-Xent loss, fused: never materialize the 8192x8192 similarity matrix.
// z = concat(z1,z2) [8192,256] f32 -> normalize -> fp8 e4m3, stored H-MAJOR:
//   zn8p[row][h*64 + s*8 + b] = zn[row][s*32 + h*8 + b]  (s=k-chunk 0..7,
//   h=lane-quarter 0..3, b=byte 0..7) -> a lane's 2 consecutive k-chunks are
//   16 contiguous bytes.
// S = zn8 zn8^T via mfma_f32_16x16x32_fp8_fp8, fused per-row sum of
// exp(2*cos - 2) (fixed logsumexp max = 2: logits bounded -> partials additive)
// nll_r = -pos_r + 2 + log(sum_r); out = mean(nll)
//
// R15 = R11 (best verified, __syncthreads loop -- pipelining arc closed after
// 3 spill regressions) with the LDS critical path fixed: B-reads widened to
// ds_read_b128 (4 reads/tile) and swizzle extended to 3 bits
// inner ^= (r16&7)<<4 -> 2-way max aliasing (free) vs prior 4-way+.
// R11 audit: LDS ~23us/CU > 16.6us MFMA floor; this puts LDS at ~8-10us.

#define NHALF 4096
#define N2 8192
#define D 256
#define CSPLIT 16
#define NPH 16      // phases per chunk; 2 tiles (32 cols) per phase
#define RPB 128     // rows per block (4 waves x 32)

typedef __attribute__((ext_vector_type(4))) float f32x4;
typedef __attribute__((ext_vector_type(2))) long longx2;

__device__ __forceinline__ unsigned char f2fp8(float f) {
  // OCP e4m3fn, RNE; inputs |f| <= 1 (normalized rows): no sat/NaN path.
  unsigned int u = __float_as_uint(f);
  unsigned char s = (unsigned char)((u >> 24) & 0x80u);
  int e = (int)((u >> 23) & 0xffu) - 127;
  unsigned int m = u & 0x7fffffu;
  if (e >= -6) {
    unsigned int r = m + 0x7ffffu + ((m >> 20) & 1u);
    if (r >= 0x800000u) { r = 0; ++e; } else r >>= 20;
    return (unsigned char)(s | (unsigned int)((e + 7) << 3) | r);
  }
  int q = (int)rintf(fabsf(f) * 512.0f);
  return (unsigned char)(s | (unsigned int)q);
}

__device__ __forceinline__ void gload_lds16(const void* g, void* l) {
  __builtin_amdgcn_global_load_lds(
      (const __attribute__((address_space(1))) unsigned int*)g,
      (__attribute__((address_space(3))) unsigned int*)l, 16, 0, 0);
}

// ---------------- Kernel 1: row-normalize to fp8, h-major permuted ----------------
__global__ __launch_bounds__(256) void norm_kernel(const float* __restrict__ z1,
                                                   const float* __restrict__ z2,
                                                   unsigned char* __restrict__ zn8p) {
  const int lane = threadIdx.x & 63;
  const int row = blockIdx.x * 4 + (threadIdx.x >> 6);
  const float* src = (row < NHALF) ? (z1 + (size_t)row * D)
                                   : (z2 + (size_t)(row - NHALF) * D);
  const float4 v = *(const float4*)(src + lane * 4);
  float ss = v.x * v.x + v.y * v.y + v.z * v.z + v.w * v.w;
  #pragma unroll
  for (int m = 1; m < 64; m <<= 1) ss += __shfl_xor(ss, m);
  const float inv = 1.0f / fmaxf(sqrtf(ss), 1e-8f);
  unsigned int o = (unsigned int)f2fp8(v.x * inv) |
                   ((unsigned int)f2fp8(v.y * inv) << 8) |
                   ((unsigned int)f2fp8(v.z * inv) << 16) |
                   ((unsigned int)f2fp8(v.w * inv) << 24);
  // k-bytes k0 = lane*4 land at permuted offset h*64 + s*8 + b.
  const int k0 = lane * 4;
  const int dest = ((k0 >> 3) & 3) * 64 + (k0 >> 5) * 8 + (k0 & 7);
  *(unsigned int*)(zn8p + (size_t)row * D + dest) = o;
}

// ---------------- Kernel 2: fused Gram + partial exp-sums ----------------
// grid (64 row-blocks, 16 col-chunks), 256 threads = 4 waves.
// Wave owns 32 rows = 2 stripes of 16; A in regs (32 VGPR); B in LDS.
// mfma_f32_16x16x32_fp8_fp8: A/B lane l -> row/col (l&15), k-bytes
//   s*32 + (l>>4)*8 ..+7 (= permuted (l>>4)*64 + s*8); D lane l -> col
//   (l&15), row 4*(l>>4)+g. (R10/R11-verified.)
// LDS B: 2 buffers x [2 tiles][16 cols][256 B permuted]; bank swizzle
// inner ^= (col&7)<<4 on stage source AND ds_read (rule #21); b128 reads
// cover k-chunks {2*s2, 2*s2+1} -> 2-way max bank aliasing (free, m136).
__global__ __launch_bounds__(256, 4) void simlse_kernel(const unsigned char* __restrict__ zn8p,
                                                        float* __restrict__ sum_ws,
                                                        float* __restrict__ pos_ws) {
  __shared__ __align__(16) char bsm[16384];  // 2 x 8 KB
  const int lane = threadIdx.x & 63;
  const int wave = threadIdx.x >> 6;
  const int r16 = lane & 15;
  const int h = lane >> 4;  // 0..3
  const int rowbase = blockIdx.x * RPB + wave * 32;
  const int cc = blockIdx.y;

  // A fragments: 2 stripes x 8 K-steps, 8B contiguous per lane (32 VGPR).
  // Permuted layout: lane (r16,h) k-chunk s lives at h*64 + s*8.
  long a[2][8];
  #pragma unroll
  for (int st = 0; st < 2; ++st) {
    const unsigned char* ap =
        zn8p + (size_t)(rowbase + st * 16 + r16) * D + h * 64;
    #pragma unroll
    for (int s = 0; s < 8; ++s) a[st][s] = *(const long*)(ap + s * 8);
  }
  #pragma unroll
  for (int st = 0; st < 2; ++st)
    #pragma unroll
    for (int s = 0; s < 8; ++s) asm volatile("" : "+v"(a[st][s]));

  float lsum[2][4];
  #pragma unroll
  for (int st = 0; st < 2; ++st)
    #pragma unroll
    for (int g = 0; g < 4; ++g) lsum[st][g] = 0.0f;

  int dt[2], pt[2];
  #pragma unroll
  for (int st = 0; st < 2; ++st) {
    dt[st] = (rowbase + st * 16) >> 4;                      // diagonal tile
    pt[st] = ((rowbase + st * 16 + NHALF) & (N2 - 1)) >> 4; // positive tile
  }

  // Stage 2 tiles (8 KB) into LDS buffer. Linear y in [0,8192): tile = y>>12,
  // col = (y>>8)&15, inner = y&255; src inner ^= (col&7)<<4 (involution,
  // 16B-aligned: XOR touches bits 4-6 only).
  auto stage = [&](int buf, int ph) {
    const int colbase = cc * 512 + ph * 32;
    #pragma unroll
    for (int s = 0; s < 2; ++s) {
      const int y = s * 4096 + wave * 1024 + lane * 16;
      const int col = (y >> 8) & 15;
      const int inner = (y & 255) ^ ((col & 7) << 4);
      const void* gp =
          zn8p + (size_t)(colbase + (y >> 12) * 16 + col) * D + inner;
      void* lp = bsm + buf * 8192 + s * 4096 + wave * 1024;  // +lane*16 by HW
      gload_lds16(gp, lp);
    }
  };

  stage(0, 0);
  __syncthreads();
  for (int ph = 0; ph < NPH; ++ph) {
    if (ph + 1 < NPH) stage((ph + 1) & 1, ph + 1);  // DMA overlaps compute
    const char* base = bsm + (ph & 1) * 8192;
    #pragma unroll
    for (int j = 0; j < 2; ++j) {
      const int ct = cc * 32 + ph * 2 + j;
      const char* tb = base + j * 4096 + r16 * 256 + h * 64;
      const int sw = (r16 & 7) << 4;
      f32x4 acc0 = (f32x4){0.f, 0.f, 0.f, 0.f};
      f32x4 acc1 = (f32x4){0.f, 0.f, 0.f, 0.f};
      #pragma unroll
      for (int s2 = 0; s2 < 4; ++s2) {
        // b128: 16 B = k-chunks {2*s2, 2*s2+1}; addr = (h*64+s2*16) ^ sw
        // relative to col base (sw bits 4-6; h*64 bit 6; s2*16 bits 4-5).
        const longx2 b =
            *(const longx2*)(tb - h * 64 + ((h * 64 + s2 * 16) ^ sw));
        acc0 = __builtin_amdgcn_mfma_f32_16x16x32_fp8_fp8(a[0][2 * s2], b[0], acc0, 0, 0, 0);
        acc1 = __builtin_amdgcn_mfma_f32_16x16x32_fp8_fp8(a[1][2 * s2], b[0], acc1, 0, 0, 0);
        acc0 = __builtin_amdgcn_mfma_f32_16x16x32_fp8_fp8(a[0][2 * s2 + 1], b[1], acc0, 0, 0, 0);
        acc1 = __builtin_amdgcn_mfma_f32_16x16x32_fp8_fp8(a[1][2 * s2 + 1], b[1], acc1, 0, 0, 0);
      }
      #pragma unroll
      for (int st = 0; st < 2; ++st) {
        const f32x4& acc = st ? acc1 : acc0;
        const bool isd = (ct == dt[st]);
        const bool isp = (ct == pt[st]);
        if (!isd && !isp) {
          #pragma unroll
          for (int g = 0; g < 4; ++g)
            lsum[st][g] += __expf(fmaf(acc[g], 2.0f, -2.0f));
        } else {
          #pragma unroll
          for (int g = 0; g < 4; ++g) {
            const int rl = (h << 2) + g;    // local row 0..15
            const bool hit = (r16 == rl);   // tile-diagonal element
            float e = __expf(fmaf(acc[g], 2.0f, -2.0f));
            if (isd && hit) e = 0.0f;       // mask self-similarity
            if (isp && hit) pos_ws[rowbase + st * 16 + rl] = acc[g] * 2.0f;
            lsum[st][g] += e;
          }
        }
      }
    }
    __syncthreads();  // drains DMA + LDS reads before buffer swap
  }

  // Reduce exp-sums across each 16-lane column group.
  #pragma unroll
  for (int st = 0; st < 2; ++st)
    #pragma unroll
    for (int g = 0; g < 4; ++g) {
      #pragma unroll
      for (int m = 1; m < 16; m <<= 1)
        lsum[st][g] += __shfl_xor(lsum[st][g], m);
    }
  if (r16 == 0) {
    #pragma unroll
    for (int st = 0; st < 2; ++st)
      #pragma unroll
      for (int g = 0; g < 4; ++g) {
        const int r = rowbase + st * 16 + (h << 2) + g;
        sum_ws[(size_t)r * CSPLIT + cc] = lsum[st][g];
      }
  }
}

// ---------------- Kernel 3a: per-row nll + per-block partial sum ----------------
__global__ __launch_bounds__(256) void nll_kernel(const float* __restrict__ sum_ws,
                                                  const float* __restrict__ pos_ws,
                                                  float* __restrict__ partial) {
  const int r = blockIdx.x * 256 + threadIdx.x;
  const float4* sp = (const float4*)(sum_ws + (size_t)r * CSPLIT);
  float t = 0.0f;
  #pragma unroll
  for (int i = 0; i < CSPLIT / 4; ++i) {
    const float4 v = sp[i];
    t += v.x + v.y + v.z + v.w;
  }
  float nll = -pos_ws[r] + 2.0f + __logf(t);
  #pragma unroll
  for (int m = 1; m < 64; m <<= 1) nll += __shfl_xor(nll, m);
  __shared__ float red[4];
  const int lane = threadIdx.x & 63;
  const int wave = threadIdx.x >> 6;
  if (lane == 0) red[wave] = nll;
  __syncthreads();
  if (threadIdx.x == 0) partial[blockIdx.x] = red[0] + red[1] + red[2] + red[3];
}

// ---------------- Kernel 3b: final mean ----------------
__global__ __launch_bounds__(64) void final_kernel(const float* __restrict__ partial,
                                                   float* __restrict__ out) {
  const int lane = threadIdx.x;
  float v = (lane < 32) ? partial[lane] : 0.0f;
  #pragma unroll
  for (int m = 1; m < 64; m <<= 1) v += __shfl_xor(v, m);
  if (lane == 0) out[0] = v * (1.0f / (float)N2);
}

extern "C" void kernel_launch(void* const* d_in, const int* in_sizes, int n_in,
                              void* d_out, int out_size, void* d_ws, size_t ws_size,
                              hipStream_t stream) {
  const float* z1 = (const float*)d_in[0];
  const float* z2 = (const float*)d_in[1];
  float* out = (float*)d_out;

  char* ws = (char*)d_ws;
  unsigned char* zn8p = (unsigned char*)ws;                 // 8192*256 = 2 MB
  float* sum_ws = (float*)(ws + (size_t)N2 * D);            // 8192*16*4 = 512 KB
  float* pos_ws = sum_ws + (size_t)N2 * CSPLIT;             // 8192*4 = 32 KB
  float* partial = pos_ws + N2;                             // 32 floats

  hipLaunchKernelGGL(norm_kernel, dim3(N2 / 4), dim3(256), 0, stream, z1, z2, zn8p);
  hipLaunchKernelGGL(simlse_kernel, dim3(N2 / RPB, CSPLIT), dim3(256), 0, stream,
                     zn8p, sum_ws, pos_ws);
  hipLaunchKernelGGL(nll_kernel, dim3(N2 / 256), dim3(256), 0, stream, sum_ws, pos_ws, partial);
  hipLaunchKernelGGL(final_kernel, dim3(1), dim3(64), 0, stream, partial, out);
}

// Round 16
// 41.751 us; speedup vs baseline: 2.1907x; 1.0128x over previous
//
#include <hip/hip_runtime.h>

// NT-Xent loss, fused: never materialize the 8192x8192 similarity matrix.
// z = concat(z1,z2) [8192,256] f32 -> normalize -> fp8 e4m3, stored H-MAJOR:
//   zn8p[row][h*64 + s*8 + b] = zn[row][s*32 + h*8 + b]  (s=k-chunk 0..7,
//   h=lane-quarter 0..3, b=byte 0..7) -> a lane's 2 consecutive k-chunks are
//   16 contiguous bytes.
// S = zn8 zn8^T via mfma_f32_16x16x32_fp8_fp8, fused per-row sum of
// exp(2*cos - 2) (fixed logsumexp max = 2: logits bounded -> partials additive)
// nll_r = -pos_r + 2 + log(sum_r); out = mean(nll)
//
// R16 = R15 (verified ~36.9us simlse: b128 B-reads + 3-bit swizzle, LDS off
// critical path) with HALF the barrier count: 4 tiles per phase (64 cols
// staged per DMA round, 2x16KB LDS, 8 phases). Per-phase compute doubles ->
// the DMA for ph+1 has 2x the window to land under, and there are 8 drains
// instead of 16. Register footprint unchanged (no spill risk).

#define NHALF 4096
#define N2 8192
#define D 256
#define CSPLIT 16
#define NPH 8       // phases per chunk; 4 tiles (64 cols) per phase
#define RPB 128     // rows per block (4 waves x 32)

typedef __attribute__((ext_vector_type(4))) float f32x4;
typedef __attribute__((ext_vector_type(2))) long longx2;

__device__ __forceinline__ unsigned char f2fp8(float f) {
  // OCP e4m3fn, RNE; inputs |f| <= 1 (normalized rows): no sat/NaN path.
  unsigned int u = __float_as_uint(f);
  unsigned char s = (unsigned char)((u >> 24) & 0x80u);
  int e = (int)((u >> 23) & 0xffu) - 127;
  unsigned int m = u & 0x7fffffu;
  if (e >= -6) {
    unsigned int r = m + 0x7ffffu + ((m >> 20) & 1u);
    if (r >= 0x800000u) { r = 0; ++e; } else r >>= 20;
    return (unsigned char)(s | (unsigned int)((e + 7) << 3) | r);
  }
  int q = (int)rintf(fabsf(f) * 512.0f);
  return (unsigned char)(s | (unsigned int)q);
}

__device__ __forceinline__ void gload_lds16(const void* g, void* l) {
  __builtin_amdgcn_global_load_lds(
      (const __attribute__((address_space(1))) unsigned int*)g,
      (__attribute__((address_space(3))) unsigned int*)l, 16, 0, 0);
}

// ---------------- Kernel 1: row-normalize to fp8, h-major permuted ----------------
__global__ __launch_bounds__(256) void norm_kernel(const float* __restrict__ z1,
                                                   const float* __restrict__ z2,
                                                   unsigned char* __restrict__ zn8p) {
  const int lane = threadIdx.x & 63;
  const int row = blockIdx.x * 4 + (threadIdx.x >> 6);
  const float* src = (row < NHALF) ? (z1 + (size_t)row * D)
                                   : (z2 + (size_t)(row - NHALF) * D);
  const float4 v = *(const float4*)(src + lane * 4);
  float ss = v.x * v.x + v.y * v.y + v.z * v.z + v.w * v.w;
  #pragma unroll
  for (int m = 1; m < 64; m <<= 1) ss += __shfl_xor(ss, m);
  const float inv = 1.0f / fmaxf(sqrtf(ss), 1e-8f);
  unsigned int o = (unsigned int)f2fp8(v.x * inv) |
                   ((unsigned int)f2fp8(v.y * inv) << 8) |
                   ((unsigned int)f2fp8(v.z * inv) << 16) |
                   ((unsigned int)f2fp8(v.w * inv) << 24);
  // k-bytes k0 = lane*4 land at permuted offset h*64 + s*8 + b.
  const int k0 = lane * 4;
  const int dest = ((k0 >> 3) & 3) * 64 + (k0 >> 5) * 8 + (k0 & 7);
  *(unsigned int*)(zn8p + (size_t)row * D + dest) = o;
}

// ---------------- Kernel 2: fused Gram + partial exp-sums ----------------
// grid (64 row-blocks, 16 col-chunks), 256 threads = 4 waves.
// Wave owns 32 rows = 2 stripes of 16; A in regs (32 VGPR); B in LDS.
// mfma_f32_16x16x32_fp8_fp8: A/B lane l -> row/col (l&15), k-bytes
//   s*32 + (l>>4)*8 ..+7 (= permuted (l>>4)*64 + s*8); D lane l -> col
//   (l&15), row 4*(l>>4)+g. (R10/R11/R15-verified.)
// LDS B: 2 buffers x [4 tiles][16 cols][256 B permuted]; bank swizzle
// inner ^= (col&7)<<4 on stage source AND ds_read (rule #21); b128 reads
// cover k-chunks {2*s2, 2*s2+1} -> 2-way max bank aliasing (free, m136).
__global__ __launch_bounds__(256, 4) void simlse_kernel(const unsigned char* __restrict__ zn8p,
                                                        float* __restrict__ sum_ws,
                                                        float* __restrict__ pos_ws) {
  __shared__ __align__(16) char bsm[32768];  // 2 x 16 KB
  const int lane = threadIdx.x & 63;
  const int wave = threadIdx.x >> 6;
  const int r16 = lane & 15;
  const int h = lane >> 4;  // 0..3
  const int rowbase = blockIdx.x * RPB + wave * 32;
  const int cc = blockIdx.y;

  // A fragments: 2 stripes x 8 K-steps, 8B contiguous per lane (32 VGPR).
  // Permuted layout: lane (r16,h) k-chunk s lives at h*64 + s*8.
  long a[2][8];
  #pragma unroll
  for (int st = 0; st < 2; ++st) {
    const unsigned char* ap =
        zn8p + (size_t)(rowbase + st * 16 + r16) * D + h * 64;
    #pragma unroll
    for (int s = 0; s < 8; ++s) a[st][s] = *(const long*)(ap + s * 8);
  }
  #pragma unroll
  for (int st = 0; st < 2; ++st)
    #pragma unroll
    for (int s = 0; s < 8; ++s) asm volatile("" : "+v"(a[st][s]));

  float lsum[2][4];
  #pragma unroll
  for (int st = 0; st < 2; ++st)
    #pragma unroll
    for (int g = 0; g < 4; ++g) lsum[st][g] = 0.0f;

  int dt[2], pt[2];
  #pragma unroll
  for (int st = 0; st < 2; ++st) {
    dt[st] = (rowbase + st * 16) >> 4;                      // diagonal tile
    pt[st] = ((rowbase + st * 16 + NHALF) & (N2 - 1)) >> 4; // positive tile
  }

  // Stage 4 tiles (16 KB) into LDS buffer. Linear y in [0,16384):
  // tile = y>>12, col = (y>>8)&15, inner = y&255; src inner ^= (col&7)<<4
  // (involution, 16B-aligned: XOR touches bits 4-6 only).
  auto stage = [&](int buf, int ph) {
    const int colbase = cc * 512 + ph * 64;
    #pragma unroll
    for (int s = 0; s < 4; ++s) {
      const int y = s * 4096 + wave * 1024 + lane * 16;
      const int col = (y >> 8) & 15;
      const int inner = (y & 255) ^ ((col & 7) << 4);
      const void* gp =
          zn8p + (size_t)(colbase + (y >> 12) * 16 + col) * D + inner;
      void* lp = bsm + buf * 16384 + s * 4096 + wave * 1024;  // +lane*16 by HW
      gload_lds16(gp, lp);
    }
  };

  stage(0, 0);
  __syncthreads();
  for (int ph = 0; ph < NPH; ++ph) {
    if (ph + 1 < NPH) stage((ph + 1) & 1, ph + 1);  // DMA overlaps compute
    const char* base = bsm + (ph & 1) * 16384;
    #pragma unroll
    for (int j = 0; j < 4; ++j) {
      const int ct = cc * 32 + ph * 4 + j;
      const char* tb = base + j * 4096 + r16 * 256;
      const int sw = (r16 & 7) << 4;
      f32x4 acc0 = (f32x4){0.f, 0.f, 0.f, 0.f};
      f32x4 acc1 = (f32x4){0.f, 0.f, 0.f, 0.f};
      #pragma unroll
      for (int s2 = 0; s2 < 4; ++s2) {
        // b128: 16 B = k-chunks {2*s2, 2*s2+1}; addr = (h*64+s2*16) ^ sw
        // (sw bits 4-6; h*64 bit 6; s2*16 bits 4-5).
        const longx2 b = *(const longx2*)(tb + ((h * 64 + s2 * 16) ^ sw));
        acc0 = __builtin_amdgcn_mfma_f32_16x16x32_fp8_fp8(a[0][2 * s2], b[0], acc0, 0, 0, 0);
        acc1 = __builtin_amdgcn_mfma_f32_16x16x32_fp8_fp8(a[1][2 * s2], b[0], acc1, 0, 0, 0);
        acc0 = __builtin_amdgcn_mfma_f32_16x16x32_fp8_fp8(a[0][2 * s2 + 1], b[1], acc0, 0, 0, 0);
        acc1 = __builtin_amdgcn_mfma_f32_16x16x32_fp8_fp8(a[1][2 * s2 + 1], b[1], acc1, 0, 0, 0);
      }
      #pragma unroll
      for (int st = 0; st < 2; ++st) {
        const f32x4& acc = st ? acc1 : acc0;
        const bool isd = (ct == dt[st]);
        const bool isp = (ct == pt[st]);
        if (!isd && !isp) {
          #pragma unroll
          for (int g = 0; g < 4; ++g)
            lsum[st][g] += __expf(fmaf(acc[g], 2.0f, -2.0f));
        } else {
          #pragma unroll
          for (int g = 0; g < 4; ++g) {
            const int rl = (h << 2) + g;    // local row 0..15
            const bool hit = (r16 == rl);   // tile-diagonal element
            float e = __expf(fmaf(acc[g], 2.0f, -2.0f));
            if (isd && hit) e = 0.0f;       // mask self-similarity
            if (isp && hit) pos_ws[rowbase + st * 16 + rl] = acc[g] * 2.0f;
            lsum[st][g] += e;
          }
        }
      }
    }
    __syncthreads();  // drains DMA + LDS reads before buffer swap
  }

  // Reduce exp-sums across each 16-lane column group.
  #pragma unroll
  for (int st = 0; st < 2; ++st)
    #pragma unroll
    for (int g = 0; g < 4; ++g) {
      #pragma unroll
      for (int m = 1; m < 16; m <<= 1)
        lsum[st][g] += __shfl_xor(lsum[st][g], m);
    }
  if (r16 == 0) {
    #pragma unroll
    for (int st = 0; st < 2; ++st)
      #pragma unroll
      for (int g = 0; g < 4; ++g) {
        const int r = rowbase + st * 16 + (h << 2) + g;
        sum_ws[(size_t)r * CSPLIT + cc] = lsum[st][g];
      }
  }
}

// ---------------- Kernel 3a: per-row nll + per-block partial sum ----------------
__global__ __launch_bounds__(256) void nll_kernel(const float* __restrict__ sum_ws,
                                                  const float* __restrict__ pos_ws,
                                                  float* __restrict__ partial) {
  const int r = blockIdx.x * 256 + threadIdx.x;
  const float4* sp = (const float4*)(sum_ws + (size_t)r * CSPLIT);
  float t = 0.0f;
  #pragma unroll
  for (int i = 0; i < CSPLIT / 4; ++i) {
    const float4 v = sp[i];
    t += v.x + v.y + v.z + v.w;
  }
  float nll = -pos_ws[r] + 2.0f + __logf(t);
  #pragma unroll
  for (int m = 1; m < 64; m <<= 1) nll += __shfl_xor(nll, m);
  __shared__ float red[4];
  const int lane = threadIdx.x & 63;
  const int wave = threadIdx.x >> 6;
  if (lane == 0) red[wave] = nll;
  __syncthreads();
  if (threadIdx.x == 0) partial[blockIdx.x] = red[0] + red[1] + red[2] + red[3];
}

// ---------------- Kernel 3b: final mean ----------------
__global__ __launch_bounds__(64) void final_kernel(const float* __restrict__ partial,
                                                   float* __restrict__ out) {
  const int lane = threadIdx.x;
  float v = (lane < 32) ? partial[lane] : 0.0f;
  #pragma unroll
  for (int m = 1; m < 64; m <<= 1) v += __shfl_xor(v, m);
  if (lane == 0) out[0] = v * (1.0f / (float)N2);
}

extern "C" void kernel_launch(void* const* d_in, const int* in_sizes, int n_in,
                              void* d_out, int out_size, void* d_ws, size_t ws_size,
                              hipStream_t stream) {
  const float* z1 = (const float*)d_in[0];
  const float* z2 = (const float*)d_in[1];
  float* out = (float*)d_out;

  char* ws = (char*)d_ws;
  unsigned char* zn8p = (unsigned char*)ws;                 // 8192*256 = 2 MB
  float* sum_ws = (float*)(ws + (size_t)N2 * D);            // 8192*16*4 = 512 KB
  float* pos_ws = sum_ws + (size_t)N2 * CSPLIT;             // 8192*4 = 32 KB
  float* partial = pos_ws + N2;                             // 32 floats

  hipLaunchKernelGGL(norm_kernel, dim3(N2 / 4), dim3(256), 0, stream, z1, z2, zn8p);
  hipLaunchKernelGGL(simlse_kernel, dim3(N2 / RPB, CSPLIT), dim3(256), 0, stream,
                     zn8p, sum_ws, pos_ws);
  hipLaunchKernelGGL(nll_kernel, dim3(N2 / 256), dim3(256), 0, stream, sum_ws, pos_ws, partial);
  hipLaunchKernelGGL(final_kernel, dim3(1), dim3(64), 0, stream, partial, out);
}

// Round 17
// 37.380 us; speedup vs baseline: 2.4468x; 1.1169x over previous
//
#include <hip/hip_runtime.h>

// NT-Xent loss, fused: never materialize the 8192x8192 similarity matrix.
// z = concat(z1,z2) [8192,256] f32 -> normalize -> fp8 e4m3 zn8 (ws, plain
// k-order). S = zn8 zn8^T via mfma_scale_f32_16x16x128_f8f6f4 (fp8/fp8,
// scale=1 -> identical numerics to plain fp8 MFMA at 2.3x the rate), fused
// per-row sum of exp(2*cos - 2) (fixed logsumexp max = 2: logits bounded ->
// partials additive). nll_r = -pos_r + 2 + log(sum_r); out = mean(nll).
//
// R17 = R16 structure with the MFMA pipe halved: per-CU audit showed
// MFMA 16.8us + LDS 10.2us running ~serialized (deep-pipeline fix spills
// 3/3 attempts). K=128 scaled MFMA drops MFMA to ~7.4us; LDS b128 count
// unchanged; C/D layout shape-determined -> epilogue identical; A = 32 VGPR.
// Scale = 0x7F (E8M0 2^0). B 32B fragment assembled from two independently
// XOR-swizzled b128 reads (bit-4 swizzle breaks 32B contiguity otherwise).

#define NHALF 4096
#define N2 8192
#define D 256
#define CSPLIT 16
#define NPH 8       // phases per chunk; 4 tiles (64 cols) per phase
#define RPB 128     // rows per block (4 waves x 32)

typedef __attribute__((ext_vector_type(4))) float f32x4;
typedef __attribute__((ext_vector_type(8))) int i32x8;

__device__ __forceinline__ unsigned char f2fp8(float f) {
  // OCP e4m3fn, RNE; inputs |f| <= 1 (normalized rows): no sat/NaN path.
  unsigned int u = __float_as_uint(f);
  unsigned char s = (unsigned char)((u >> 24) & 0x80u);
  int e = (int)((u >> 23) & 0xffu) - 127;
  unsigned int m = u & 0x7fffffu;
  if (e >= -6) {
    unsigned int r = m + 0x7ffffu + ((m >> 20) & 1u);
    if (r >= 0x800000u) { r = 0; ++e; } else r >>= 20;
    return (unsigned char)(s | (unsigned int)((e + 7) << 3) | r);
  }
  int q = (int)rintf(fabsf(f) * 512.0f);
  return (unsigned char)(s | (unsigned int)q);
}

__device__ __forceinline__ void gload_lds16(const void* g, void* l) {
  __builtin_amdgcn_global_load_lds(
      (const __attribute__((address_space(1))) unsigned int*)g,
      (__attribute__((address_space(3))) unsigned int*)l, 16, 0, 0);
}

// ---------------- Kernel 1: row-normalize to fp8 (plain k-order) ----------------
__global__ __launch_bounds__(256) void norm_kernel(const float* __restrict__ z1,
                                                   const float* __restrict__ z2,
                                                   unsigned char* __restrict__ zn8) {
  const int lane = threadIdx.x & 63;
  const int row = blockIdx.x * 4 + (threadIdx.x >> 6);
  const float* src = (row < NHALF) ? (z1 + (size_t)row * D)
                                   : (z2 + (size_t)(row - NHALF) * D);
  const float4 v = *(const float4*)(src + lane * 4);
  float ss = v.x * v.x + v.y * v.y + v.z * v.z + v.w * v.w;
  #pragma unroll
  for (int m = 1; m < 64; m <<= 1) ss += __shfl_xor(ss, m);
  const float inv = 1.0f / fmaxf(sqrtf(ss), 1e-8f);
  unsigned int o = (unsigned int)f2fp8(v.x * inv) |
                   ((unsigned int)f2fp8(v.y * inv) << 8) |
                   ((unsigned int)f2fp8(v.z * inv) << 16) |
                   ((unsigned int)f2fp8(v.w * inv) << 24);
  *(unsigned int*)(zn8 + (size_t)row * D + lane * 4) = o;
}

// ---------------- Kernel 2: fused Gram + partial exp-sums ----------------
// grid (64 row-blocks, 16 col-chunks), 256 threads = 4 waves.
// Wave owns 32 rows = 2 stripes of 16; A in regs (32 VGPR); B in LDS.
// mfma_scale_f32_16x16x128_f8f6f4 (fp8/fp8, scale 2^0):
//   A/B lane l -> row/col (l&15), k-bytes 32*(l>>4)..+31 per instruction
//   (inst s covers k in [128s,128s+128)); D lane l -> col (l&15),
//   row 4*(l>>4)+g  (shape-determined, same as 16x16x32 -- m121-128).
// LDS B: 2 buffers x [4 tiles][16 cols][256 B]; swizzle inner ^= (col&7)<<4
// on stage source AND each 16B ds_read independently (rule #21).
__global__ __launch_bounds__(256, 4) void simlse_kernel(const unsigned char* __restrict__ zn8,
                                                        float* __restrict__ sum_ws,
                                                        float* __restrict__ pos_ws) {
  __shared__ __align__(16) char bsm[32768];  // 2 x 16 KB
  const int lane = threadIdx.x & 63;
  const int wave = threadIdx.x >> 6;
  const int r16 = lane & 15;
  const int h = lane >> 4;  // 0..3
  const int rowbase = blockIdx.x * RPB + wave * 32;
  const int cc = blockIdx.y;

  // A fragments: 2 stripes x 2 K-insts, 32B contiguous per lane (32 VGPR).
  i32x8 a[2][2];
  #pragma unroll
  for (int st = 0; st < 2; ++st) {
    const unsigned char* ap =
        zn8 + (size_t)(rowbase + st * 16 + r16) * D + h * 32;
    #pragma unroll
    for (int s = 0; s < 2; ++s) a[st][s] = *(const i32x8*)(ap + s * 128);
  }
  #pragma unroll
  for (int st = 0; st < 2; ++st)
    #pragma unroll
    for (int s = 0; s < 2; ++s) asm volatile("" : "+v"(a[st][s]));

  float lsum[2][4];
  #pragma unroll
  for (int st = 0; st < 2; ++st)
    #pragma unroll
    for (int g = 0; g < 4; ++g) lsum[st][g] = 0.0f;

  int dt[2], pt[2];
  #pragma unroll
  for (int st = 0; st < 2; ++st) {
    dt[st] = (rowbase + st * 16) >> 4;                      // diagonal tile
    pt[st] = ((rowbase + st * 16 + NHALF) & (N2 - 1)) >> 4; // positive tile
  }

  // Stage 4 tiles (16 KB) into LDS buffer. Linear y in [0,16384):
  // tile = y>>12, col = (y>>8)&15, inner = y&255; src inner ^= (col&7)<<4
  // (involution, 16B-aligned: XOR touches bits 4-6 only).
  auto stage = [&](int buf, int ph) {
    const int colbase = cc * 512 + ph * 64;
    #pragma unroll
    for (int s = 0; s < 4; ++s) {
      const int y = s * 4096 + wave * 1024 + lane * 16;
      const int col = (y >> 8) & 15;
      const int inner = (y & 255) ^ ((col & 7) << 4);
      const void* gp =
          zn8 + (size_t)(colbase + (y >> 12) * 16 + col) * D + inner;
      void* lp = bsm + buf * 16384 + s * 4096 + wave * 1024;  // +lane*16 by HW
      gload_lds16(gp, lp);
    }
  };

  stage(0, 0);
  __syncthreads();
  for (int ph = 0; ph < NPH; ++ph) {
    if (ph + 1 < NPH) stage((ph + 1) & 1, ph + 1);  // DMA overlaps compute
    const char* base = bsm + (ph & 1) * 16384;
    #pragma unroll
    for (int j = 0; j < 4; ++j) {
      const int ct = cc * 32 + ph * 4 + j;
      const char* tb = base + j * 4096 + r16 * 256;
      const int sw = (r16 & 7) << 4;
      f32x4 acc0 = (f32x4){0.f, 0.f, 0.f, 0.f};
      f32x4 acc1 = (f32x4){0.f, 0.f, 0.f, 0.f};
      #pragma unroll
      for (int s = 0; s < 2; ++s) {
        // 32B B-fragment = two b128, each independently XOR-swizzled
        // (bit-4 swizzle would otherwise swap the 16B halves).
        const int o = s * 128 + h * 32;
        const int4 lo = *(const int4*)(tb + (o ^ sw));
        const int4 hi = *(const int4*)(tb + ((o + 16) ^ sw));
        const i32x8 b = {lo.x, lo.y, lo.z, lo.w, hi.x, hi.y, hi.z, hi.w};
        acc0 = __builtin_amdgcn_mfma_scale_f32_16x16x128_f8f6f4(
            a[0][s], b, acc0, 0, 0, 0, 0x7F7F7F7F, 0, 0x7F7F7F7F);
        acc1 = __builtin_amdgcn_mfma_scale_f32_16x16x128_f8f6f4(
            a[1][s], b, acc1, 0, 0, 0, 0x7F7F7F7F, 0, 0x7F7F7F7F);
      }
      #pragma unroll
      for (int st = 0; st < 2; ++st) {
        const f32x4& acc = st ? acc1 : acc0;
        const bool isd = (ct == dt[st]);
        const bool isp = (ct == pt[st]);
        if (!isd && !isp) {
          #pragma unroll
          for (int g = 0; g < 4; ++g)
            lsum[st][g] += __expf(fmaf(acc[g], 2.0f, -2.0f));
        } else {
          #pragma unroll
          for (int g = 0; g < 4; ++g) {
            const int rl = (h << 2) + g;    // local row 0..15
            const bool hit = (r16 == rl);   // tile-diagonal element
            float e = __expf(fmaf(acc[g], 2.0f, -2.0f));
            if (isd && hit) e = 0.0f;       // mask self-similarity
            if (isp && hit) pos_ws[rowbase + st * 16 + rl] = acc[g] * 2.0f;
            lsum[st][g] += e;
          }
        }
      }
    }
    __syncthreads();  // drains DMA + LDS reads before buffer swap
  }

  // Reduce exp-sums across each 16-lane column group.
  #pragma unroll
  for (int st = 0; st < 2; ++st)
    #pragma unroll
    for (int g = 0; g < 4; ++g) {
      #pragma unroll
      for (int m = 1; m < 16; m <<= 1)
        lsum[st][g] += __shfl_xor(lsum[st][g], m);
    }
  if (r16 == 0) {
    #pragma unroll
    for (int st = 0; st < 2; ++st)
      #pragma unroll
      for (int g = 0; g < 4; ++g) {
        const int r = rowbase + st * 16 + (h << 2) + g;
        sum_ws[(size_t)r * CSPLIT + cc] = lsum[st][g];
      }
  }
}

// ---------------- Kernel 3a: per-row nll + per-block partial sum ----------------
__global__ __launch_bounds__(256) void nll_kernel(const float* __restrict__ sum_ws,
                                                  const float* __restrict__ pos_ws,
                                                  float* __restrict__ partial) {
  const int r = blockIdx.x * 256 + threadIdx.x;
  const float4* sp = (const float4*)(sum_ws + (size_t)r * CSPLIT);
  float t = 0.0f;
  #pragma unroll
  for (int i = 0; i < CSPLIT / 4; ++i) {
    const float4 v = sp[i];
    t += v.x + v.y + v.z + v.w;
  }
  float nll = -pos_ws[r] + 2.0f + __logf(t);
  #pragma unroll
  for (int m = 1; m < 64; m <<= 1) nll += __shfl_xor(nll, m);
  __shared__ float red[4];
  const int lane = threadIdx.x & 63;
  const int wave = threadIdx.x >> 6;
  if (lane == 0) red[wave] = nll;
  __syncthreads();
  if (threadIdx.x == 0) partial[blockIdx.x] = red[0] + red[1] + red[2] + red[3];
}

// ---------------- Kernel 3b: final mean ----------------
__global__ __launch_bounds__(64) void final_kernel(const float* __restrict__ partial,
                                                   float* __restrict__ out) {
  const int lane = threadIdx.x;
  float v = (lane < 32) ? partial[lane] : 0.0f;
  #pragma unroll
  for (int m = 1; m < 64; m <<= 1) v += __shfl_xor(v, m);
  if (lane == 0) out[0] = v * (1.0f / (float)N2);
}

extern "C" void kernel_launch(void* const* d_in, const int* in_sizes, int n_in,
                              void* d_out, int out_size, void* d_ws, size_t ws_size,
                              hipStream_t stream) {
  const float* z1 = (const float*)d_in[0];
  const float* z2 = (const float*)d_in[1];
  float* out = (float*)d_out;

  char* ws = (char*)d_ws;
  unsigned char* zn8 = (unsigned char*)ws;                  // 8192*256 = 2 MB
  float* sum_ws = (float*)(ws + (size_t)N2 * D);            // 8192*16*4 = 512 KB
  float* pos_ws = sum_ws + (size_t)N2 * CSPLIT;             // 8192*4 = 32 KB
  float* partial = pos_ws + N2;                             // 32 floats

  hipLaunchKernelGGL(norm_kernel, dim3(N2 / 4), dim3(256), 0, stream, z1, z2, zn8);
  hipLaunchKernelGGL(simlse_kernel, dim3(N2 / RPB, CSPLIT), dim3(256), 0, stream,
                     zn8, sum_ws, pos_ws);
  hipLaunchKernelGGL(nll_kernel, dim3(N2 / 256), dim3(256), 0, stream, sum_ws, pos_ws, partial);
  hipLaunchKernelGGL(final_kernel, dim3(1), dim3(64), 0, stream, partial, out);
}